// Round 15
// baseline (669.820 us; speedup 1.0000x reference)
//
#include <hip/hip_runtime.h>
#include <hip/hip_bf16.h>
#include <cstdint>

#define RINGN 256
#define DD    128
#define SDN   42
#define G3N   126
#define INN   64
#define BN    512
#define TN    512
#define NCN   1000
#define HS    44          // padded h row stride (floats)
#define GXS   128         // gx ring slot stride (floats)
#define BT    (BN * TN)
#define HSLOTS 32         // h ring slots
#define GSLOTS 16         // gx ring slots
#define WCS   66          // LDS Wc row stride (pad: 2-way bank alias only)

typedef float v2f __attribute__((ext_vector_type(2)));
typedef float4 __attribute__((may_alias)) f4ma;
typedef float2 __attribute__((may_alias)) f2ma;

__device__ __forceinline__ float sigm(float x)    { return 1.0f / (1.0f + __expf(-x)); }
__device__ __forceinline__ float tanhfast(float x){ float e = __expf(2.0f * x); return 1.0f - 2.0f / (e + 1.0f); }
__device__ __forceinline__ float wrap256(float x) { return x - 256.0f * floorf(x * 0.00390625f); }

__device__ __forceinline__ void taps_norm(float p, int* pos, float* w) {
  float base = floorf(p);
  float frac = p - base;
  int ib = (int)base;
  float e[5];
  float s = 0.0f;
#pragma unroll
  for (int k = 0; k < 5; k++) {
    float d = (float)(k - 2) - frac;
    e[k] = __expf(-(d * d) * 0.125f);
    s += e[k];
    pos[k] = (ib + k - 2) & 255;
  }
  float inv = 1.0f / s;
#pragma unroll
  for (int k = 0; k < 5; k++) w[k] = e[k] * inv;
}

// DPP full-wave sum, result broadcast via readlane(63)
template<int C>
__device__ __forceinline__ float dpp_add_step(float x) {
  int t = __builtin_amdgcn_update_dpp(0, __float_as_int(x), C, 0xf, 0xf, true);
  return x + __int_as_float(t);
}
__device__ __forceinline__ float wave_sum64(float x) {
  x = dpp_add_step<0x111>(x);
  x = dpp_add_step<0x112>(x);
  x = dpp_add_step<0x114>(x);
  x = dpp_add_step<0x118>(x);
  x = dpp_add_step<0x142>(x);
  x = dpp_add_step<0x143>(x);
  return __int_as_float(__builtin_amdgcn_readlane(__float_as_int(x), 63));
}

// ---------------- prep ----------------
__global__ void prep_kernel(const float* __restrict__ w_ih, const float* __restrict__ w_proj,
                            const float* __restrict__ b_proj, const float* __restrict__ b_ih,
                            float* __restrict__ Wc, float* __restrict__ bc) {
  int idx = blockIdx.x * 256 + threadIdx.x;
  if (idx < G3N * INN) {
    int j = idx / INN, i = idx % INN;
    float a = 0.0f;
    for (int k = 0; k < SDN; k++) a += w_ih[j * SDN + k] * w_proj[k * INN + i];
    Wc[idx] = a;
  }
  if (idx < G3N) {
    float a = b_ih[idx];
    for (int k = 0; k < SDN; k++) a += w_ih[idx * SDN + k] * b_proj[k];
    bc[idx] = a;
  }
}

// ---------------- fused recurrence: 4-wave spin-poll pipeline ----------------
// wave3: gx producer (Wc in LDS -> low VGPR). wave0: GRU. wave1: bridge. wave2: ptr/JG.
__global__ __launch_bounds__(256, 1)
void rec4_kernel(const float* __restrict__ x,        // [B][T][64]
                 const float* __restrict__ Wc,       // [126][64]
                 const float* __restrict__ bc,       // [126]
                 const float* __restrict__ w_hh, const float* __restrict__ b_hh,
                 const float* __restrict__ w_bridge, const float* __restrict__ b_bridge,
                 const float* __restrict__ w_jump, const float* __restrict__ b_jump,
                 const float* __restrict__ w_gate, const float* __restrict__ b_gate,
                 const float* __restrict__ theta,
                 float* __restrict__ hbuf, float* __restrict__ ptrbuf) {
  const int tid = threadIdx.x;
  const int wid = tid >> 6;
  const int lane = tid & 63;
  const int b = blockIdx.x;

  __shared__ float2 JG[RINGN];
  __shared__ __align__(16) float h_ring[HSLOTS * HS];
  __shared__ __align__(16) float gx_ring[GSLOTS * GXS];
  __shared__ __align__(16) float xst[2 * INN];
  __shared__ __align__(16) float WcS66[G3N * WCS];   // 33 KB
  __shared__ float ringJ[TN];
  __shared__ float ringG[TN];
  __shared__ int flagH;   // wave0 -> wave1 (+ wave3 backpressure)
  __shared__ int done1;   // wave1 -> wave2 (+ wave0 backpressure)
  __shared__ int flagG;   // wave3 -> wave0

  if (tid == 0) { flagH = 0; done1 = 0; flagG = 0; }
  __syncthreads();

  if (wid == 3) {
    // ================= WAVE3: gx producer (weights in LDS) =================
    // stage Wc -> LDS (one time; scattered LDS writes, coalesced global reads)
    for (int idx = lane; idx < G3N * INN; idx += 64) {
      WcS66[(idx >> 6) * WCS + (idx & 63)] = Wc[idx];
    }
    asm volatile("s_waitcnt lgkmcnt(0)" ::: "memory");
    __builtin_amdgcn_wave_barrier();

    const int c1 = (lane < 62) ? (64 + lane) : 125;   // clamped second row
    const float bcv0 = bc[lane];
    const float bcv1 = (lane < 62) ? bc[64 + lane] : 0.0f;
    const f2ma* w0 = (const f2ma*)&WcS66[lane * WCS];
    const f2ma* w1 = (const f2ma*)&WcS66[c1 * WCS];

    const float* xb = x + (size_t)b * TN * INN;
    // 4-deep x prefetch
    float xcur = xb[lane];
    float xn1 = xb[INN + lane];
    float xn2 = xb[2 * INN + lane];
    float xn3 = xb[3 * INN + lane];

    volatile int* fH = &flagH;
    volatile int* fG = &flagG;

    for (int t = 0; t < TN; t++) {
      if ((t & 3) == 0 && t >= 12) {
        while (*fH < t - 12) __builtin_amdgcn_s_sleep(1);
      }
      // stage x row t
      float* xs = &xst[(t & 1) * INN];
      xs[lane] = xcur;
      __builtin_amdgcn_wave_barrier();
      asm volatile("" ::: "memory");
      // compute gx row (BIT-IDENTICAL accumulation: v2f single-acc, i ascending)
      const f2ma* xp = (const f2ma*)xs;
      v2f acc0 = (v2f){bcv0, 0.0f};
      v2f acc1 = (v2f){bcv1, 0.0f};
#pragma unroll
      for (int i = 0; i < 32; i++) {
        float2 xv = xp[i];
        v2f xr = (v2f){xv.x, xv.y};
        float2 wv0 = w0[i];
        float2 wv1 = w1[i];
        acc0 = __builtin_elementwise_fma((v2f){wv0.x, wv0.y}, xr, acc0);
        acc1 = __builtin_elementwise_fma((v2f){wv1.x, wv1.y}, xr, acc1);
      }
      float* slot = &gx_ring[(t & (GSLOTS - 1)) * GXS];
      slot[lane] = acc0.x + acc0.y;
      if (lane < 62) slot[64 + lane] = acc1.x + acc1.y;
      asm volatile("s_waitcnt lgkmcnt(0)" ::: "memory");
      if (lane == 0) *fG = t + 1;
      // rotate x prefetch (distance 4)
      xcur = xn1; xn1 = xn2; xn2 = xn3;
      if (t + 4 < TN) xn3 = xb[(size_t)(t + 4) * INN + lane];
    }
  } else if (wid == 0) {
    // ================= WAVE0: GRU recurrence =================
    const int jj = (lane < SDN) ? lane : (SDN - 1);

    const v2f* whh2 = (const v2f*)w_hh;
    v2f Whr[21], Whz[21], Whn[21];
#pragma unroll
    for (int k = 0; k < 21; k++) {
      Whr[k] = whh2[jj * 21 + k];
      Whz[k] = whh2[(jj + SDN) * 21 + k];
      Whn[k] = whh2[(jj + 2 * SDN) * 21 + k];
    }
    const float bhr = b_hh[jj], bhz = b_hh[jj + SDN], bhn = b_hh[jj + 2 * SDN];

    v2f hv2[22];
#pragma unroll
    for (int k = 0; k < 22; k++) hv2[k] = (v2f){0.f, 0.f};
    float hprev = 0.0f;

    const int o0 = jj, o1 = SDN + jj, o2 = 2 * SDN + jj;
    float* hb = hbuf + (size_t)b * TN * HS;

    volatile int* fH = &flagH;
    volatile int* fC = &done1;
    volatile int* fG = &flagG;
    int seenG = 0;

    // prologue: gx row 0
    if (seenG < 1) { while ((seenG = *fG) < 1) __builtin_amdgcn_s_sleep(1); }
    asm volatile("" ::: "memory");
    float cu0 = gx_ring[o0], cu1 = gx_ring[o1], cu2 = gx_ring[o2];

    for (int t = 0; t < TN; t++) {
      // backpressure on wave1 (h ring reuse)
      if ((t & 7) == 0 && t >= HSLOTS) {
        while (*fC < t - 24) __builtin_amdgcn_s_sleep(1);
      }
      // ---- GRU matvec + gates (verbatim) ----
      v2f ar = (v2f){bhr, 0.f}, az = (v2f){bhz, 0.f}, an = (v2f){bhn, 0.f};
#pragma unroll
      for (int k = 0; k < 21; k++) {
        v2f h2 = hv2[k];
        ar = __builtin_elementwise_fma(Whr[k], h2, ar);
        az = __builtin_elementwise_fma(Whz[k], h2, az);
        an = __builtin_elementwise_fma(Whn[k], h2, an);
      }
      float ghr = ar.x + ar.y, ghz = az.x + az.y, ghn = an.x + an.y;
      float rgate = sigm(cu0 + ghr);
      float zg = sigm(cu1 + ghz);
      float ng = tanhfast(cu2 + rgate * ghn);
      float hn = (1.0f - zg) * ng + zg * hprev;
      hprev = hn;

      float* slot = &h_ring[(t & (HSLOTS - 1)) * HS];
      if (lane < SDN) {
        slot[lane] = hn;
        hb[(size_t)t * HS + lane] = hn;   // fire-and-forget global
      }
      asm volatile("s_waitcnt lgkmcnt(0)" ::: "memory");
      if (lane == 0) *fH = t + 1;
      __builtin_amdgcn_wave_barrier();
      asm volatile("" ::: "memory");

      // read back h' (verbatim pattern)
#pragma unroll
      for (int k4 = 0; k4 < 11; k4++) {
        float4 v = *(const f4ma*)(&slot[k4 * 4]);
        hv2[2 * k4]     = (v2f){v.x, v.y};
        hv2[2 * k4 + 1] = (v2f){v.z, v.w};
      }

      // prefetch gx(t+1) from ring
      if (t + 1 < TN) {
        if (seenG < t + 2) {
          while ((seenG = *fG) < t + 2) __builtin_amdgcn_s_sleep(1);
        }
        asm volatile("" ::: "memory");
        const float* gs = &gx_ring[((t + 1) & (GSLOTS - 1)) * GXS];
        cu0 = gs[o0]; cu1 = gs[o1]; cu2 = gs[o2];
      }
    }
  } else if (wid == 1) {
    // ================= WAVE1: bridge + projections =================
    const int r1 = lane + 64;
    const v2f* wb2 = (const v2f*)w_bridge;
    v2f Wb0[21], Wb1[21];
#pragma unroll
    for (int k = 0; k < 21; k++) {
      Wb0[k] = wb2[lane * 21 + k];
      Wb1[k] = wb2[r1 * 21 + k];
    }
    const float bb0 = b_bridge[lane], bb1 = b_bridge[r1];
    const float wj0 = w_jump[lane], wj1 = w_jump[r1];
    const float wg0 = w_gate[lane], wg1 = w_gate[r1];

    volatile int* fH = &flagH;
    volatile int* fC = &done1;
    int seenH = 0;

    for (int t = 0; t < TN; t++) {
      if (seenH <= t) {
        while ((seenH = *fH) <= t) __builtin_amdgcn_s_sleep(1);
      }
      asm volatile("" ::: "memory");
      const float* slot = &h_ring[(t & (HSLOTS - 1)) * HS];
      v2f hw[22];
#pragma unroll
      for (int k4 = 0; k4 < 11; k4++) {
        float4 v = *(const f4ma*)(&slot[k4 * 4]);
        hw[2 * k4]     = (v2f){v.x, v.y};
        hw[2 * k4 + 1] = (v2f){v.z, v.w};
      }
      // bridge matvec + tanh (verbatim)
      v2f a0 = (v2f){bb0, 0.f}, a1 = (v2f){bb1, 0.f};
#pragma unroll
      for (int k = 0; k < 21; k++) {
        v2f h2 = hw[k];
        a0 = __builtin_elementwise_fma(Wb0[k], h2, a0);
        a1 = __builtin_elementwise_fma(Wb1[k], h2, a1);
      }
      float u0 = tanhfast(a0.x + a0.y);
      float u1 = tanhfast(a1.x + a1.y);

      float pjs = wave_sum64(u0 * wj0 + u1 * wj1);
      float pgs = wave_sum64(u0 * wg0 + u1 * wg1);

      if (lane == 0) { ringJ[t] = pjs; ringG[t] = pgs; }
      asm volatile("s_waitcnt lgkmcnt(0)" ::: "memory");
      if (lane == 0) *fC = t + 1;
    }
  } else {
    // ================= WAVE2: pointer/J/G chain =================
    for (int i = lane; i < RINGN; i += 64) JG[i] = make_float2(0.f, 0.f);
    __builtin_amdgcn_wave_barrier();
    asm volatile("" ::: "memory");

    const float bj = b_jump[0], bg = b_gate[0];
    float ptr = wrap256(theta[0]);
    float* pb = ptrbuf + (size_t)b * TN;

    float wk[5]; float2 Vk[5];
    {
      int posk[5];
      taps_norm(ptr, posk, wk);
#pragma unroll
      for (int k = 0; k < 5; k++) Vk[k] = JG[posk[k]];
    }
    float pjprev = 0.f, pgprev = 0.f, S2prev = 0.f;
    volatile int* rdy = &done1;
    int seen = 0;

    for (int t = 0; t < TN; t++) {
      float dotJ = 0.f, dotG = 0.f;
#pragma unroll
      for (int k = 0; k < 5; k++) { dotJ += wk[k] * Vk[k].x; dotG += wk[k] * Vk[k].y; }
      float Jv = fmaf(pjprev, S2prev, dotJ);
      float Gv = fmaf(pgprev, S2prev, dotG);
      float jump = 256.0f * sigm(Jv + bj);
      float gate = sigm(Gv + bg);
      float delta = wrap256(jump - ptr + 128.0f) - 128.0f;
      float ptr2 = wrap256(ptr + gate * delta);

      float tbase = floorf(ptr2);
      float frac = ptr2 - tbase;
      int ib = (int)tbase;
      float e2[5], ssum = 0.f; int pos2[5];
#pragma unroll
      for (int k = 0; k < 5; k++) {
        float d = (float)(k - 2) - frac;
        e2[k] = __expf(-(d * d) * 0.125f);
        ssum += e2[k];
        pos2[k] = (ib + k - 2) & 255;
      }
      float inv2 = 1.0f / ssum;
      float2 Vk2[5];
#pragma unroll
      for (int k = 0; k < 5; k++) Vk2[k] = JG[pos2[k]];
      float w2n[5], S2 = 0.f;
#pragma unroll
      for (int k = 0; k < 5; k++) { w2n[k] = e2[k] * inv2; S2 = fmaf(w2n[k], w2n[k], S2); }
      if (lane == 0) pb[t] = ptr2;

      if (seen <= t) {
        while ((seen = *rdy) <= t) __builtin_amdgcn_s_sleep(1);
      }
      asm volatile("" ::: "memory");
      float pjs = ringJ[t];
      float pgs = ringG[t];

      // scatter: plain stores using preread Vk2 (bit-identical to atomicAdd; sole writer)
      int p2sel = pos2[0]; float w2sel = w2n[0]; float2 vsel = Vk2[0];
#pragma unroll
      for (int k = 1; k < 5; k++) {
        if (lane == k) { p2sel = pos2[k]; w2sel = w2n[k]; vsel = Vk2[k]; }
      }
      if (lane < 5) {
        JG[p2sel] = make_float2(vsel.x + w2sel * pjs, vsel.y + w2sel * pgs);
      }

#pragma unroll
      for (int k = 0; k < 5; k++) { wk[k] = w2n[k]; Vk[k] = Vk2[k]; }
      S2prev = S2; pjprev = pjs; pgprev = pgs; ptr = ptr2;
    }
  }
}

// ---------------- r reconstruction ----------------
__global__ __launch_bounds__(64)
void rfinal_kernel(const float* __restrict__ hbuf, const float* __restrict__ ptrbuf,
                   const float* __restrict__ w_bridge, const float* __restrict__ b_bridge,
                   float* __restrict__ rbuf) {
  const int b = blockIdx.x;
  const int chunk = blockIdx.y;
  const int lane = threadIdx.x;
  const int t0 = chunk * 128;
  const int r1 = lane + 64;

  __shared__ float c_lds[128];

  const float* pb = ptrbuf + (size_t)b * TN;
  float ptrf = pb[TN - 1];
  int posf[5]; float wf[5];
  taps_norm(ptrf, posf, wf);

#pragma unroll
  for (int rr = 0; rr < 2; rr++) {
    int tt = rr * 64 + lane;
    int p2[5]; float w2[5];
    taps_norm(pb[t0 + tt], p2, w2);
    float c = 0.0f;
#pragma unroll
    for (int k = 0; k < 5; k++)
#pragma unroll
      for (int k2 = 0; k2 < 5; k2++)
        c += (posf[k] == p2[k2]) ? wf[k] * w2[k2] : 0.0f;
    c_lds[tt] = c;
  }
  __builtin_amdgcn_wave_barrier();
  asm volatile("" ::: "memory");

  const v2f* wb2 = (const v2f*)w_bridge;
  v2f Wb0[21], Wb1[21];
#pragma unroll
  for (int k = 0; k < 21; k++) { Wb0[k] = wb2[lane * 21 + k]; Wb1[k] = wb2[r1 * 21 + k]; }
  float bb0 = b_bridge[lane], bb1 = b_bridge[r1];

  float racc0 = 0.0f, racc1 = 0.0f;
  for (int tt = 0; tt < 128; tt++) {
    float ct = c_lds[tt];
    if (ct != 0.0f) {
      const f4ma* hp = (const f4ma*)(hbuf + ((size_t)b * TN + t0 + tt) * HS);
      v2f hx[22];
#pragma unroll
      for (int i = 0; i < 11; i++) {
        float4 v = hp[i];
        hx[2 * i]     = (v2f){v.x, v.y};
        hx[2 * i + 1] = (v2f){v.z, v.w};
      }
      v2f a0 = (v2f){bb0, 0.f}, a1 = (v2f){bb1, 0.f};
#pragma unroll
      for (int k = 0; k < 21; k++) {
        a0 = __builtin_elementwise_fma(Wb0[k], hx[k], a0);
        a1 = __builtin_elementwise_fma(Wb1[k], hx[k], a1);
      }
      racc0 += ct * tanhfast(a0.x + a0.y);
      racc1 += ct * tanhfast(a1.x + a1.y);
    }
  }
  atomicAdd(&rbuf[b * DD + lane], racc0);
  atomicAdd(&rbuf[b * DD + 64 + lane], racc1);
}

// ---------------- classifier: 4 batch rows per block ----------------
__global__ __launch_bounds__(256)
void cls_kernel(const float* __restrict__ rbuf, const float* __restrict__ w_cls,
                const float* __restrict__ b_cls, float* __restrict__ out) {
  const int b0 = blockIdx.x * 4;
  const int tid = threadIdx.x;
  __shared__ __align__(16) float r[4 * DD];
  for (int i = tid; i < 4 * DD; i += 256) r[i] = rbuf[(size_t)b0 * DD + i];
  __syncthreads();

  for (int c = tid; c < NCN; c += 256) {
    float bcv = b_cls[c];
    float a0 = bcv, a1 = bcv, a2 = bcv, a3 = bcv;
    const float* wrow = &w_cls[(size_t)c * DD];
#pragma unroll
    for (int d4 = 0; d4 < DD / 4; d4++) {
      float4 wv = *reinterpret_cast<const float4*>(&wrow[d4 * 4]);
      float4 r0 = *(const f4ma*)(&r[0 * DD + d4 * 4]);
      float4 r1 = *(const f4ma*)(&r[1 * DD + d4 * 4]);
      float4 r2 = *(const f4ma*)(&r[2 * DD + d4 * 4]);
      float4 r3 = *(const f4ma*)(&r[3 * DD + d4 * 4]);
      a0 += wv.x * r0.x + wv.y * r0.y + wv.z * r0.z + wv.w * r0.w;
      a1 += wv.x * r1.x + wv.y * r1.y + wv.z * r1.z + wv.w * r1.w;
      a2 += wv.x * r2.x + wv.y * r2.y + wv.z * r2.z + wv.w * r2.w;
      a3 += wv.x * r3.x + wv.y * r3.y + wv.z * r3.z + wv.w * r3.w;
    }
    out[(size_t)(b0 + 0) * NCN + c] = a0;
    out[(size_t)(b0 + 1) * NCN + c] = a1;
    out[(size_t)(b0 + 2) * NCN + c] = a2;
    out[(size_t)(b0 + 3) * NCN + c] = a3;
  }
}

extern "C" void kernel_launch(void* const* d_in, const int* in_sizes, int n_in,
                              void* d_out, int out_size, void* d_ws, size_t ws_size,
                              hipStream_t stream) {
  const float* x        = (const float*)d_in[0];
  const float* theta    = (const float*)d_in[1];
  const float* w_proj   = (const float*)d_in[2];
  const float* b_proj   = (const float*)d_in[3];
  const float* w_ih     = (const float*)d_in[4];
  const float* w_hh     = (const float*)d_in[5];
  const float* b_ih     = (const float*)d_in[6];
  const float* b_hh     = (const float*)d_in[7];
  const float* w_bridge = (const float*)d_in[8];
  const float* b_bridge = (const float*)d_in[9];
  const float* w_jump   = (const float*)d_in[10];
  const float* b_jump   = (const float*)d_in[11];
  const float* w_gate   = (const float*)d_in[12];
  const float* b_gate   = (const float*)d_in[13];
  const float* w_cls    = (const float*)d_in[14];
  const float* b_cls    = (const float*)d_in[15];
  float* out = (float*)d_out;

  char* ws = (char*)d_ws;
  size_t off = 0;
  float* hbuf   = (float*)(ws + off); off += (size_t)BN * TN * HS * 4;
  float* ptrbuf = (float*)(ws + off); off += (size_t)BN * TN * 4;
  float* rbuf   = (float*)(ws + off); off += (size_t)BN * DD * 4;
  float* Wc     = (float*)(ws + off); off += (((size_t)G3N * INN * 4 + 255) & ~(size_t)255);
  float* bc     = (float*)(ws + off); off += 512;

  hipMemsetAsync(rbuf, 0, (size_t)BN * DD * 4, stream);
  prep_kernel<<<32, 256, 0, stream>>>(w_ih, w_proj, b_proj, b_ih, Wc, bc);
  rec4_kernel<<<BN, 256, 0, stream>>>(x, Wc, bc, w_hh, b_hh, w_bridge, b_bridge,
                                      w_jump, b_jump, w_gate, b_gate, theta, hbuf, ptrbuf);
  dim3 gfin(BN, 4);
  rfinal_kernel<<<gfin, 64, 0, stream>>>(hbuf, ptrbuf, w_bridge, b_bridge, rbuf);
  cls_kernel<<<BN / 4, 256, 0, stream>>>(rbuf, w_cls, b_cls, out);
}

// Round 16
// 503.016 us; speedup vs baseline: 1.3316x; 1.3316x over previous
//
#include <hip/hip_runtime.h>
#include <hip/hip_bf16.h>
#include <cstdint>

#define RINGN 256
#define DD    128
#define SDN   42
#define G3N   126
#define INN   64
#define BN    512
#define TN    512
#define NCN   1000
#define HS    44          // padded h row stride (floats)
#define GXS   128         // padded gx row stride (floats) -> 512B rows
#define BT    (BN * TN)
#define HSLOTS 32         // h ring slots

typedef float v2f __attribute__((ext_vector_type(2)));
typedef float4 __attribute__((may_alias)) f4ma;
typedef float2 __attribute__((may_alias)) f2ma;

__device__ __forceinline__ float sigm(float x)    { return 1.0f / (1.0f + __expf(-x)); }
__device__ __forceinline__ float tanhfast(float x){ float e = __expf(2.0f * x); return 1.0f - 2.0f / (e + 1.0f); }
__device__ __forceinline__ float wrap256(float x) { return x - 256.0f * floorf(x * 0.00390625f); }

// pin a v2f's components into VGPRs: values become asm results the allocator
// cannot rematerialize from memory (defeats the reload-per-iteration heuristic).
__device__ __forceinline__ void pin2(v2f& w) {
  float a = w.x, b = w.y;
  asm volatile("" : "+v"(a), "+v"(b));
  w = (v2f){a, b};
}
__device__ __forceinline__ void pin1(float& a) {
  asm volatile("" : "+v"(a));
}

__device__ __forceinline__ void taps_norm(float p, int* pos, float* w) {
  float base = floorf(p);
  float frac = p - base;
  int ib = (int)base;
  float e[5];
  float s = 0.0f;
#pragma unroll
  for (int k = 0; k < 5; k++) {
    float d = (float)(k - 2) - frac;
    e[k] = __expf(-(d * d) * 0.125f);
    s += e[k];
    pos[k] = (ib + k - 2) & 255;
  }
  float inv = 1.0f / s;
#pragma unroll
  for (int k = 0; k < 5; k++) w[k] = e[k] * inv;
}

// DPP full-wave sum, result broadcast via readlane(63)
template<int C>
__device__ __forceinline__ float dpp_add_step(float x) {
  int t = __builtin_amdgcn_update_dpp(0, __float_as_int(x), C, 0xf, 0xf, true);
  return x + __int_as_float(t);
}
__device__ __forceinline__ float wave_sum64(float x) {
  x = dpp_add_step<0x111>(x);
  x = dpp_add_step<0x112>(x);
  x = dpp_add_step<0x114>(x);
  x = dpp_add_step<0x118>(x);
  x = dpp_add_step<0x142>(x);
  x = dpp_add_step<0x143>(x);
  return __int_as_float(__builtin_amdgcn_readlane(__float_as_int(x), 63));
}

// ---------------- prep ----------------
__global__ void prep_kernel(const float* __restrict__ w_ih, const float* __restrict__ w_proj,
                            const float* __restrict__ b_proj, const float* __restrict__ b_ih,
                            float* __restrict__ Wc, float* __restrict__ bc) {
  int idx = blockIdx.x * 256 + threadIdx.x;
  if (idx < G3N * INN) {
    int j = idx / INN, i = idx % INN;
    float a = 0.0f;
    for (int k = 0; k < SDN; k++) a += w_ih[j * SDN + k] * w_proj[k * INN + i];
    Wc[idx] = a;
  }
  if (idx < G3N) {
    float a = b_ih[idx];
    for (int k = 0; k < SDN; k++) a += w_ih[idx * SDN + k] * b_proj[k];
    bc[idx] = a;
  }
}

// ---------------- gx GEMM: gxp[row][c] padded rows, LDS-staged coalesced writes ----------------
// NOTE: inner-loop accumulation MUST stay the v2f single-accumulator form (bit-identical
// to the passing rounds). The pointer recurrence is discretely chaotic: re-associating
// this sum flips floor() buckets downstream and diverges trajectories (rounds 6/7).
__global__ __launch_bounds__(256)
void gx_gemm(const float* __restrict__ x, const float* __restrict__ Wc,
             const float* __restrict__ bc, float* __restrict__ gxp) {
  __shared__ __align__(16) float WcS[G3N * INN];
  __shared__ float bcS[G3N + 2];
  __shared__ float tileS[256 * 33];
  const int tid = threadIdx.x;
  const float4* wc4 = (const float4*)Wc;
  float4* wcs4 = (float4*)WcS;
  for (int i = tid; i < G3N * INN / 4; i += 256) wcs4[i] = wc4[i];
  if (tid < G3N) bcS[tid] = bc[tid];
  __syncthreads();

  const size_t row0 = (size_t)blockIdx.x * 256;
  const size_t row = row0 + tid;
  v2f xr[INN / 2];
#pragma unroll
  for (int i = 0; i < INN / 4; i++) {
    float4 v = *reinterpret_cast<const float4*>(&x[row * INN + i * 4]);
    xr[2 * i]     = (v2f){v.x, v.y};
    xr[2 * i + 1] = (v2f){v.z, v.w};
  }

  for (int c0 = 0; c0 < GXS; c0 += 32) {
#pragma unroll
    for (int cc = 0; cc < 32; cc++) {
      int c = c0 + cc;
      float val = 0.0f;
      if (c < G3N) {
        const v2f* w = (const v2f*)&WcS[c * INN];
        v2f acc2 = (v2f){bcS[c], 0.0f};
#pragma unroll
        for (int i = 0; i < INN / 2; i++) acc2 = __builtin_elementwise_fma(w[i], xr[i], acc2);
        val = acc2.x + acc2.y;
      }
      tileS[tid * 33 + cc] = val;
    }
    __syncthreads();
#pragma unroll
    for (int i = 0; i < 8; i++) {
      int f = i * 256 + tid;
      int r = f >> 3;
      int cc4 = (f & 7) * 4;
      float4 v = make_float4(tileS[r * 33 + cc4], tileS[r * 33 + cc4 + 1],
                             tileS[r * 33 + cc4 + 2], tileS[r * 33 + cc4 + 3]);
      *reinterpret_cast<float4*>(&gxp[(row0 + r) * GXS + c0 + cc4]) = v;
    }
    __syncthreads();
  }
}

// ---------------- fused recurrence: 3-wave spin-poll pipeline (round-12 structure) ----------------
// wave0: GRU recurrence. wave1: bridge+projections (+hbuf store). wave2: pointer/J/G chain.
__global__ __launch_bounds__(192, 1)
void rec3_kernel(const float* __restrict__ gxp,      // [BT][GXS]
                 const float* __restrict__ w_hh, const float* __restrict__ b_hh,
                 const float* __restrict__ w_bridge, const float* __restrict__ b_bridge,
                 const float* __restrict__ w_jump, const float* __restrict__ b_jump,
                 const float* __restrict__ w_gate, const float* __restrict__ b_gate,
                 const float* __restrict__ theta,
                 float* __restrict__ hbuf, float* __restrict__ ptrbuf) {
  const int tid = threadIdx.x;
  const int wid = tid >> 6;
  const int lane = tid & 63;
  const int b = blockIdx.x;

  __shared__ float2 JG[RINGN];
  __shared__ __align__(16) float h_ring[HSLOTS * HS];
  __shared__ float ringJ[TN];
  __shared__ float ringG[TN];
  __shared__ int flagH;   // wave0 -> wave1
  __shared__ int done1;   // wave1 -> {wave0 backpressure, wave2 data}

  if (tid == 0) { flagH = 0; done1 = 0; }
  __syncthreads();

  if (wid == 0) {
    // ================= WAVE0: GRU recurrence =================
    const int jj = (lane < SDN) ? lane : (SDN - 1);

    const v2f* whh2 = (const v2f*)w_hh;
    v2f Whr[21], Whz[21], Whn[21];
#pragma unroll
    for (int k = 0; k < 21; k++) {
      Whr[k] = whh2[jj * 21 + k];
      Whz[k] = whh2[(jj + SDN) * 21 + k];
      Whn[k] = whh2[(jj + 2 * SDN) * 21 + k];
    }
    float bhr = b_hh[jj], bhz = b_hh[jj + SDN], bhn = b_hh[jj + 2 * SDN];
    // pin all weights into VGPRs (defeat rematerialization)
#pragma unroll
    for (int k = 0; k < 21; k++) { pin2(Whr[k]); pin2(Whz[k]); pin2(Whn[k]); }
    pin1(bhr); pin1(bhz); pin1(bhn);

    v2f hv2[22];
#pragma unroll
    for (int k = 0; k < 22; k++) hv2[k] = (v2f){0.f, 0.f};
    float hprev = 0.0f;

    const float* gxr = gxp + (size_t)b * TN * GXS;
    const int o0 = jj, o1 = SDN + jj, o2 = 2 * SDN + jj;

    float pA0 = gxr[o0], pA1 = gxr[o1], pA2 = gxr[o2];
    float pB0 = gxr[GXS + o0], pB1 = gxr[GXS + o1], pB2 = gxr[GXS + o2];

    volatile int* fH = &flagH;
    volatile int* fC = &done1;

    auto STEP = [&](int t, float pgx0, float pgx1, float pgx2) {
      if ((t & 7) == 0 && t >= HSLOTS) {
        while (*fC < t - 24) __builtin_amdgcn_s_sleep(1);
      }
      v2f ar = (v2f){bhr, 0.f}, az = (v2f){bhz, 0.f}, an = (v2f){bhn, 0.f};
#pragma unroll
      for (int k = 0; k < 21; k++) {
        v2f h2 = hv2[k];
        ar = __builtin_elementwise_fma(Whr[k], h2, ar);
        az = __builtin_elementwise_fma(Whz[k], h2, az);
        an = __builtin_elementwise_fma(Whn[k], h2, an);
      }
      float ghr = ar.x + ar.y, ghz = az.x + az.y, ghn = an.x + an.y;
      float rgate = sigm(pgx0 + ghr);
      float zg = sigm(pgx1 + ghz);
      float ng = tanhfast(pgx2 + rgate * ghn);
      float hn = (1.0f - zg) * ng + zg * hprev;
      hprev = hn;

      float* slot = &h_ring[(t & (HSLOTS - 1)) * HS];
      if (lane < SDN) slot[lane] = hn;
      asm volatile("s_waitcnt lgkmcnt(0)" ::: "memory");
      if (lane == 0) *fH = t + 1;
      __builtin_amdgcn_wave_barrier();
      asm volatile("" ::: "memory");

#pragma unroll
      for (int k4 = 0; k4 < 11; k4++) {
        float4 v = *(const f4ma*)(&slot[k4 * 4]);
        hv2[2 * k4]     = (v2f){v.x, v.y};
        hv2[2 * k4 + 1] = (v2f){v.z, v.w};
      }
    };

    for (int t = 0; t < TN; t += 2) {
      STEP(t, pA0, pA1, pA2);
      if (t + 2 < TN) {
        const float* g = gxr + (size_t)(t + 2) * GXS;
        pA0 = g[o0]; pA1 = g[o1]; pA2 = g[o2];
      }
      STEP(t + 1, pB0, pB1, pB2);
      if (t + 3 < TN) {
        const float* g = gxr + (size_t)(t + 3) * GXS;
        pB0 = g[o0]; pB1 = g[o1]; pB2 = g[o2];
      }
    }
  } else if (wid == 1) {
    // ================= WAVE1: bridge + projections + hbuf store =================
    const int r1 = lane + 64;
    const v2f* wb2 = (const v2f*)w_bridge;
    v2f Wb0[21], Wb1[21];
#pragma unroll
    for (int k = 0; k < 21; k++) {
      Wb0[k] = wb2[lane * 21 + k];
      Wb1[k] = wb2[r1 * 21 + k];
    }
    float bb0 = b_bridge[lane], bb1 = b_bridge[r1];
    float wj0 = w_jump[lane], wj1 = w_jump[r1];
    float wg0 = w_gate[lane], wg1 = w_gate[r1];
#pragma unroll
    for (int k = 0; k < 21; k++) { pin2(Wb0[k]); pin2(Wb1[k]); }
    pin1(bb0); pin1(bb1); pin1(wj0); pin1(wj1); pin1(wg0); pin1(wg1);

    float* hb = hbuf + (size_t)b * TN * HS;
    volatile int* fH = &flagH;
    volatile int* fC = &done1;
    int seenH = 0;

    for (int t = 0; t < TN; t++) {
      if (seenH <= t) {
        while ((seenH = *fH) <= t) __builtin_amdgcn_s_sleep(1);
      }
      asm volatile("" ::: "memory");
      const float* slot = &h_ring[(t & (HSLOTS - 1)) * HS];
      v2f hw[22];
#pragma unroll
      for (int k4 = 0; k4 < 11; k4++) {
        float4 v = *(const f4ma*)(&slot[k4 * 4]);
        hw[2 * k4]     = (v2f){v.x, v.y};
        hw[2 * k4 + 1] = (v2f){v.z, v.w};
      }
      // fire-and-forget h store to global (moved off wave0's serial chain)
      if (lane < SDN) hb[(size_t)t * HS + lane] = slot[lane];

      v2f a0 = (v2f){bb0, 0.f}, a1 = (v2f){bb1, 0.f};
#pragma unroll
      for (int k = 0; k < 21; k++) {
        v2f h2 = hw[k];
        a0 = __builtin_elementwise_fma(Wb0[k], h2, a0);
        a1 = __builtin_elementwise_fma(Wb1[k], h2, a1);
      }
      float u0 = tanhfast(a0.x + a0.y);
      float u1 = tanhfast(a1.x + a1.y);

      float pjs = wave_sum64(u0 * wj0 + u1 * wj1);
      float pgs = wave_sum64(u0 * wg0 + u1 * wg1);

      if (lane == 0) { ringJ[t] = pjs; ringG[t] = pgs; }
      asm volatile("s_waitcnt lgkmcnt(0)" ::: "memory");
      if (lane == 0) *fC = t + 1;
    }
  } else {
    // ================= WAVE2: pointer/J/G chain =================
    for (int i = lane; i < RINGN; i += 64) JG[i] = make_float2(0.f, 0.f);
    __builtin_amdgcn_wave_barrier();
    asm volatile("" ::: "memory");

    const float bj = b_jump[0], bg = b_gate[0];
    float ptr = wrap256(theta[0]);
    float* pb = ptrbuf + (size_t)b * TN;

    float wk[5]; float2 Vk[5];
    {
      int posk[5];
      taps_norm(ptr, posk, wk);
#pragma unroll
      for (int k = 0; k < 5; k++) Vk[k] = JG[posk[k]];
    }
    float pjprev = 0.f, pgprev = 0.f, S2prev = 0.f;
    volatile int* rdy = &done1;
    int seen = 0;

    for (int t = 0; t < TN; t++) {
      float dotJ = 0.f, dotG = 0.f;
#pragma unroll
      for (int k = 0; k < 5; k++) { dotJ += wk[k] * Vk[k].x; dotG += wk[k] * Vk[k].y; }
      float Jv = fmaf(pjprev, S2prev, dotJ);
      float Gv = fmaf(pgprev, S2prev, dotG);
      float jump = 256.0f * sigm(Jv + bj);
      float gate = sigm(Gv + bg);
      float delta = wrap256(jump - ptr + 128.0f) - 128.0f;
      float ptr2 = wrap256(ptr + gate * delta);

      float tbase = floorf(ptr2);
      float frac = ptr2 - tbase;
      int ib = (int)tbase;
      float e2[5], ssum = 0.f; int pos2[5];
#pragma unroll
      for (int k = 0; k < 5; k++) {
        float d = (float)(k - 2) - frac;
        e2[k] = __expf(-(d * d) * 0.125f);
        ssum += e2[k];
        pos2[k] = (ib + k - 2) & 255;
      }
      float inv2 = 1.0f / ssum;
      float2 Vk2[5];
#pragma unroll
      for (int k = 0; k < 5; k++) Vk2[k] = JG[pos2[k]];
      float w2n[5], S2 = 0.f;
#pragma unroll
      for (int k = 0; k < 5; k++) { w2n[k] = e2[k] * inv2; S2 = fmaf(w2n[k], w2n[k], S2); }
      if (lane == 0) pb[t] = ptr2;

      if (seen <= t) {
        while ((seen = *rdy) <= t) __builtin_amdgcn_s_sleep(1);
      }
      asm volatile("" ::: "memory");
      float pjs = ringJ[t];
      float pgs = ringG[t];

      int p2sel = pos2[0]; float w2sel = w2n[0];
#pragma unroll
      for (int k = 1; k < 5; k++) {
        if (lane == k) { p2sel = pos2[k]; w2sel = w2n[k]; }
      }
      if (lane < 5) {
        atomicAdd(&JG[p2sel].x, w2sel * pjs);
        atomicAdd(&JG[p2sel].y, w2sel * pgs);
      }

#pragma unroll
      for (int k = 0; k < 5; k++) { wk[k] = w2n[k]; Vk[k] = Vk2[k]; }
      S2prev = S2; pjprev = pjs; pgprev = pgs; ptr = ptr2;
    }
  }
}

// ---------------- r reconstruction ----------------
__global__ __launch_bounds__(64)
void rfinal_kernel(const float* __restrict__ hbuf, const float* __restrict__ ptrbuf,
                   const float* __restrict__ w_bridge, const float* __restrict__ b_bridge,
                   float* __restrict__ rbuf) {
  const int b = blockIdx.x;
  const int chunk = blockIdx.y;
  const int lane = threadIdx.x;
  const int t0 = chunk * 128;
  const int r1 = lane + 64;

  __shared__ float c_lds[128];

  const float* pb = ptrbuf + (size_t)b * TN;
  float ptrf = pb[TN - 1];
  int posf[5]; float wf[5];
  taps_norm(ptrf, posf, wf);

#pragma unroll
  for (int rr = 0; rr < 2; rr++) {
    int tt = rr * 64 + lane;
    int p2[5]; float w2[5];
    taps_norm(pb[t0 + tt], p2, w2);
    float c = 0.0f;
#pragma unroll
    for (int k = 0; k < 5; k++)
#pragma unroll
      for (int k2 = 0; k2 < 5; k2++)
        c += (posf[k] == p2[k2]) ? wf[k] * w2[k2] : 0.0f;
    c_lds[tt] = c;
  }
  __builtin_amdgcn_wave_barrier();
  asm volatile("" ::: "memory");

  const v2f* wb2 = (const v2f*)w_bridge;
  v2f Wb0[21], Wb1[21];
#pragma unroll
  for (int k = 0; k < 21; k++) { Wb0[k] = wb2[lane * 21 + k]; Wb1[k] = wb2[r1 * 21 + k]; }
  float bb0 = b_bridge[lane], bb1 = b_bridge[r1];

  float racc0 = 0.0f, racc1 = 0.0f;
  for (int tt = 0; tt < 128; tt++) {
    float ct = c_lds[tt];
    if (ct != 0.0f) {
      const f4ma* hp = (const f4ma*)(hbuf + ((size_t)b * TN + t0 + tt) * HS);
      v2f hx[22];
#pragma unroll
      for (int i = 0; i < 11; i++) {
        float4 v = hp[i];
        hx[2 * i]     = (v2f){v.x, v.y};
        hx[2 * i + 1] = (v2f){v.z, v.w};
      }
      v2f a0 = (v2f){bb0, 0.f}, a1 = (v2f){bb1, 0.f};
#pragma unroll
      for (int k = 0; k < 21; k++) {
        a0 = __builtin_elementwise_fma(Wb0[k], hx[k], a0);
        a1 = __builtin_elementwise_fma(Wb1[k], hx[k], a1);
      }
      racc0 += ct * tanhfast(a0.x + a0.y);
      racc1 += ct * tanhfast(a1.x + a1.y);
    }
  }
  atomicAdd(&rbuf[b * DD + lane], racc0);
  atomicAdd(&rbuf[b * DD + 64 + lane], racc1);
}

// ---------------- classifier: 4 batch rows per block ----------------
__global__ __launch_bounds__(256)
void cls_kernel(const float* __restrict__ rbuf, const float* __restrict__ w_cls,
                const float* __restrict__ b_cls, float* __restrict__ out) {
  const int b0 = blockIdx.x * 4;
  const int tid = threadIdx.x;
  __shared__ __align__(16) float r[4 * DD];
  for (int i = tid; i < 4 * DD; i += 256) r[i] = rbuf[(size_t)b0 * DD + i];
  __syncthreads();

  for (int c = tid; c < NCN; c += 256) {
    float bcv = b_cls[c];
    float a0 = bcv, a1 = bcv, a2 = bcv, a3 = bcv;
    const float* wrow = &w_cls[(size_t)c * DD];
#pragma unroll
    for (int d4 = 0; d4 < DD / 4; d4++) {
      float4 wv = *reinterpret_cast<const float4*>(&wrow[d4 * 4]);
      float4 r0 = *(const f4ma*)(&r[0 * DD + d4 * 4]);
      float4 r1 = *(const f4ma*)(&r[1 * DD + d4 * 4]);
      float4 r2 = *(const f4ma*)(&r[2 * DD + d4 * 4]);
      float4 r3 = *(const f4ma*)(&r[3 * DD + d4 * 4]);
      a0 += wv.x * r0.x + wv.y * r0.y + wv.z * r0.z + wv.w * r0.w;
      a1 += wv.x * r1.x + wv.y * r1.y + wv.z * r1.z + wv.w * r1.w;
      a2 += wv.x * r2.x + wv.y * r2.y + wv.z * r2.z + wv.w * r2.w;
      a3 += wv.x * r3.x + wv.y * r3.y + wv.z * r3.z + wv.w * r3.w;
    }
    out[(size_t)(b0 + 0) * NCN + c] = a0;
    out[(size_t)(b0 + 1) * NCN + c] = a1;
    out[(size_t)(b0 + 2) * NCN + c] = a2;
    out[(size_t)(b0 + 3) * NCN + c] = a3;
  }
}

extern "C" void kernel_launch(void* const* d_in, const int* in_sizes, int n_in,
                              void* d_out, int out_size, void* d_ws, size_t ws_size,
                              hipStream_t stream) {
  const float* x        = (const float*)d_in[0];
  const float* theta    = (const float*)d_in[1];
  const float* w_proj   = (const float*)d_in[2];
  const float* b_proj   = (const float*)d_in[3];
  const float* w_ih     = (const float*)d_in[4];
  const float* w_hh     = (const float*)d_in[5];
  const float* b_ih     = (const float*)d_in[6];
  const float* b_hh     = (const float*)d_in[7];
  const float* w_bridge = (const float*)d_in[8];
  const float* b_bridge = (const float*)d_in[9];
  const float* w_jump   = (const float*)d_in[10];
  const float* b_jump   = (const float*)d_in[11];
  const float* w_gate   = (const float*)d_in[12];
  const float* b_gate   = (const float*)d_in[13];
  const float* w_cls    = (const float*)d_in[14];
  const float* b_cls    = (const float*)d_in[15];
  float* out = (float*)d_out;

  char* ws = (char*)d_ws;
  size_t off = 0;
  float* gxp    = (float*)(ws + off); off += (size_t)BT * GXS * 4;
  float* hbuf   = (float*)(ws + off); off += (size_t)BN * TN * HS * 4;
  float* ptrbuf = (float*)(ws + off); off += (size_t)BN * TN * 4;
  float* rbuf   = (float*)(ws + off); off += (size_t)BN * DD * 4;
  float* Wc     = (float*)(ws + off); off += (((size_t)G3N * INN * 4 + 255) & ~(size_t)255);
  float* bc     = (float*)(ws + off); off += 512;

  hipMemsetAsync(rbuf, 0, (size_t)BN * DD * 4, stream);
  prep_kernel<<<32, 256, 0, stream>>>(w_ih, w_proj, b_proj, b_ih, Wc, bc);
  gx_gemm<<<BT / 256, 256, 0, stream>>>(x, Wc, bc, gxp);
  rec3_kernel<<<BN, 192, 0, stream>>>(gxp, w_hh, b_hh, w_bridge, b_bridge,
                                      w_jump, b_jump, w_gate, b_gate, theta, hbuf, ptrbuf);
  dim3 gfin(BN, 4);
  rfinal_kernel<<<gfin, 64, 0, stream>>>(hbuf, ptrbuf, w_bridge, b_bridge, rbuf);
  cls_kernel<<<BN / 4, 256, 0, stream>>>(rbuf, w_cls, b_cls, out);
}